// Round 1
// baseline (161.147 us; speedup 1.0000x reference)
//
#include <hip/hip_runtime.h>

#define IN_DIM  3
#define HID_DIM 20
#define OUT_DIM 3
#define N_EXP   5
#define ELEMS   8
#define BLOCK   256

// d_out layout: mixed [B,3] followed by gate [B,5], both fp32.

__global__ __launch_bounds__(BLOCK) void moe_kernel(
    const float* __restrict__ x,
    const float* __restrict__ W1,   // [E, IN, HID]
    const float* __restrict__ b1,   // [E, HID]
    const float* __restrict__ W2,   // [E, HID, OUT]
    const float* __restrict__ b2,   // [E, OUT]
    const float* __restrict__ Wg,   // [IN, E]
    const float* __restrict__ bg,   // [E]
    float* __restrict__ out,
    int B)
{
    __shared__ float sW1[N_EXP * IN_DIM * HID_DIM];   // 300
    __shared__ float sB1[N_EXP * HID_DIM];            // 100
    __shared__ float sW2[N_EXP * HID_DIM * OUT_DIM];  // 300
    __shared__ float sB2[N_EXP * OUT_DIM];            // 15
    __shared__ float sWg[IN_DIM * N_EXP];             // 15
    __shared__ float sBg[N_EXP];                      // 5

    {
        const int t = threadIdx.x;
        for (int i = t; i < N_EXP * IN_DIM * HID_DIM; i += BLOCK) sW1[i] = W1[i];
        for (int i = t; i < N_EXP * HID_DIM; i += BLOCK)          sB1[i] = b1[i];
        for (int i = t; i < N_EXP * HID_DIM * OUT_DIM; i += BLOCK) sW2[i] = W2[i];
        if (t < N_EXP * OUT_DIM) sB2[t] = b2[t];
        if (t < IN_DIM * N_EXP)  sWg[t] = Wg[t];
        if (t < N_EXP)           sBg[t] = bg[t];
    }
    __syncthreads();

    const long long base =
        ((long long)blockIdx.x * BLOCK + threadIdx.x) * ELEMS;
    if (base >= (long long)B) return;

    float* __restrict__ mixed_out = out;
    float* __restrict__ gate_out  = out + (long long)B * OUT_DIM;

    if (base + ELEMS <= (long long)B) {
        // ---------- load x: 24 floats = 6 float4 (16B aligned: base%8==0) ----
        float xf[ELEMS * IN_DIM];
        {
            const float4* xp = reinterpret_cast<const float4*>(x + base * IN_DIM);
            #pragma unroll
            for (int i = 0; i < (ELEMS * IN_DIM) / 4; ++i) {
                float4 v = xp[i];
                xf[4 * i + 0] = v.x; xf[4 * i + 1] = v.y;
                xf[4 * i + 2] = v.z; xf[4 * i + 3] = v.w;
            }
        }

        // ---------- gate: softmax(x @ Wg + bg) -------------------------------
        float gate[ELEMS][N_EXP];
        #pragma unroll
        for (int q = 0; q < ELEMS; ++q) {
            float lg[N_EXP];
            #pragma unroll
            for (int e = 0; e < N_EXP; ++e) {
                float t = sBg[e];
                #pragma unroll
                for (int i = 0; i < IN_DIM; ++i)
                    t = fmaf(xf[q * IN_DIM + i], sWg[i * N_EXP + e], t);
                lg[e] = t;
            }
            float m = lg[0];
            #pragma unroll
            for (int e = 1; e < N_EXP; ++e) m = fmaxf(m, lg[e]);
            float s = 0.f;
            #pragma unroll
            for (int e = 0; e < N_EXP; ++e) { lg[e] = __expf(lg[e] - m); s += lg[e]; }
            const float inv = 1.0f / s;
            #pragma unroll
            for (int e = 0; e < N_EXP; ++e) gate[q][e] = lg[e] * inv;
        }

        // ---------- experts: streamed over hidden units ----------------------
        float mix[ELEMS][OUT_DIM];
        #pragma unroll
        for (int q = 0; q < ELEMS; ++q)
            #pragma unroll
            for (int k = 0; k < OUT_DIM; ++k) mix[q][k] = 0.f;

        #pragma unroll
        for (int e = 0; e < N_EXP; ++e) {
            float oacc[ELEMS][OUT_DIM];
            #pragma unroll
            for (int q = 0; q < ELEMS; ++q)
                #pragma unroll
                for (int k = 0; k < OUT_DIM; ++k)
                    oacc[q][k] = sB2[e * OUT_DIM + k];

            #pragma unroll
            for (int j = 0; j < HID_DIM; ++j) {
                // 7 wave-uniform LDS reads reused across 8 elements (56 FMAs)
                const float w10 = sW1[(e * IN_DIM + 0) * HID_DIM + j];
                const float w11 = sW1[(e * IN_DIM + 1) * HID_DIM + j];
                const float w12 = sW1[(e * IN_DIM + 2) * HID_DIM + j];
                const float bb  = sB1[e * HID_DIM + j];
                const float w20 = sW2[(e * HID_DIM + j) * OUT_DIM + 0];
                const float w21 = sW2[(e * HID_DIM + j) * OUT_DIM + 1];
                const float w22 = sW2[(e * HID_DIM + j) * OUT_DIM + 2];
                #pragma unroll
                for (int q = 0; q < ELEMS; ++q) {
                    float h = fmaf(xf[q * IN_DIM + 2], w12,
                              fmaf(xf[q * IN_DIM + 1], w11,
                              fmaf(xf[q * IN_DIM + 0], w10, bb)));
                    h = fmaxf(h, 0.f);
                    oacc[q][0] = fmaf(h, w20, oacc[q][0]);
                    oacc[q][1] = fmaf(h, w21, oacc[q][1]);
                    oacc[q][2] = fmaf(h, w22, oacc[q][2]);
                }
            }

            #pragma unroll
            for (int q = 0; q < ELEMS; ++q)
                #pragma unroll
                for (int k = 0; k < OUT_DIM; ++k)
                    mix[q][k] = fmaf(gate[q][e], oacc[q][k], mix[q][k]);
        }

        // ---------- store mixed: 24 floats = 6 float4 ------------------------
        {
            float4* mp = reinterpret_cast<float4*>(mixed_out + base * OUT_DIM);
            #pragma unroll
            for (int i = 0; i < (ELEMS * OUT_DIM) / 4; ++i) {
                float4 v;
                v.x = mix[(4 * i + 0) / OUT_DIM][(4 * i + 0) % OUT_DIM];
                v.y = mix[(4 * i + 1) / OUT_DIM][(4 * i + 1) % OUT_DIM];
                v.z = mix[(4 * i + 2) / OUT_DIM][(4 * i + 2) % OUT_DIM];
                v.w = mix[(4 * i + 3) / OUT_DIM][(4 * i + 3) % OUT_DIM];
                mp[i] = v;
            }
        }
        // ---------- store gate: 40 floats = 10 float4 ------------------------
        {
            float4* gp = reinterpret_cast<float4*>(gate_out + base * N_EXP);
            #pragma unroll
            for (int i = 0; i < (ELEMS * N_EXP) / 4; ++i) {
                float4 v;
                v.x = gate[(4 * i + 0) / N_EXP][(4 * i + 0) % N_EXP];
                v.y = gate[(4 * i + 1) / N_EXP][(4 * i + 1) % N_EXP];
                v.z = gate[(4 * i + 2) / N_EXP][(4 * i + 2) % N_EXP];
                v.w = gate[(4 * i + 3) / N_EXP][(4 * i + 3) % N_EXP];
                gp[i] = v;
            }
        }
    } else {
        // ---------- scalar tail (B not divisible by BLOCK*ELEMS) -------------
        for (long long b = base; b < (long long)B; ++b) {
            float xv[IN_DIM];
            for (int i = 0; i < IN_DIM; ++i) xv[i] = x[b * IN_DIM + i];

            float lg[N_EXP];
            for (int e = 0; e < N_EXP; ++e) {
                float t = sBg[e];
                for (int i = 0; i < IN_DIM; ++i)
                    t = fmaf(xv[i], sWg[i * N_EXP + e], t);
                lg[e] = t;
            }
            float m = lg[0];
            for (int e = 1; e < N_EXP; ++e) m = fmaxf(m, lg[e]);
            float s = 0.f;
            for (int e = 0; e < N_EXP; ++e) { lg[e] = __expf(lg[e] - m); s += lg[e]; }
            const float inv = 1.0f / s;
            for (int e = 0; e < N_EXP; ++e) lg[e] *= inv;

            float mixv[OUT_DIM] = {0.f, 0.f, 0.f};
            for (int e = 0; e < N_EXP; ++e) {
                float oa[OUT_DIM];
                for (int k = 0; k < OUT_DIM; ++k) oa[k] = sB2[e * OUT_DIM + k];
                for (int j = 0; j < HID_DIM; ++j) {
                    float h = sB1[e * HID_DIM + j];
                    for (int i = 0; i < IN_DIM; ++i)
                        h = fmaf(xv[i], sW1[(e * IN_DIM + i) * HID_DIM + j], h);
                    h = fmaxf(h, 0.f);
                    for (int k = 0; k < OUT_DIM; ++k)
                        oa[k] = fmaf(h, sW2[(e * HID_DIM + j) * OUT_DIM + k], oa[k]);
                }
                for (int k = 0; k < OUT_DIM; ++k)
                    mixv[k] = fmaf(lg[e], oa[k], mixv[k]);
            }
            for (int k = 0; k < OUT_DIM; ++k) mixed_out[b * OUT_DIM + k] = mixv[k];
            for (int e = 0; e < N_EXP; ++e)  gate_out[b * N_EXP + e] = lg[e];
        }
    }
}

extern "C" void kernel_launch(void* const* d_in, const int* in_sizes, int n_in,
                              void* d_out, int out_size, void* d_ws, size_t ws_size,
                              hipStream_t stream) {
    const float* x  = (const float*)d_in[0];
    const float* W1 = (const float*)d_in[1];
    const float* b1 = (const float*)d_in[2];
    const float* W2 = (const float*)d_in[3];
    const float* b2 = (const float*)d_in[4];
    const float* Wg = (const float*)d_in[5];
    const float* bg = (const float*)d_in[6];
    float* out = (float*)d_out;

    const int B = in_sizes[0] / IN_DIM;
    const int per_block = BLOCK * ELEMS;
    const int grid = (B + per_block - 1) / per_block;

    moe_kernel<<<grid, BLOCK, 0, stream>>>(x, W1, b1, W2, b2, Wg, bg, out, B);
}